// Round 4
// baseline (145.625 us; speedup 1.0000x reference)
//
#include <hip/hip_runtime.h>

// Problem constants: x [32,112,112,128] fp32, W [7,7,2,1] HWIO, b [1]
static constexpr int Bn = 32;
static constexpr int Hn = 112;
static constexpr int Wn = 112;
static constexpr int Cn = 128;                 // channels (32 float4 per pixel)
static constexpr int STRIP  = 14;              // rows per block
static constexpr int NSTRIP = Hn / STRIP;      // 8 strips/image -> 256 blocks total
static constexpr int HALO   = 3;               // 7x7 SAME conv
static constexpr int SROWS  = STRIP + 2*HALO;  // 20 stat rows (incl halo)
static constexpr int SCOLS  = Wn + 2*HALO;     // 118 stat cols (zero-padded)

typedef float floatx4 __attribute__((ext_vector_type(4)));

// ---------------------------------------------------------------------------
// One fused kernel. Block = (image b, 14-row strip). Phases:
//  1) stats (mean,max over 128 ch) for strip+halo rows -> LDS (zero-padded;
//     zero-pad is EXACT for SAME conv because conv is linear in merged input)
//  2) 7x7x2 conv + bias + sigmoid -> gate in LDS
//  3) re-read strip's x (hot in L2/L3: this block streamed it in phase 1),
//     multiply by gate, non-temporal store to out.
// Halo x-rows are also read by the adjacent strip's block (concurrent) ->
// second reader hits L3, so HBM read volume stays ~1.0x of x.
// ---------------------------------------------------------------------------
__global__ __launch_bounds__(512) void fused_kernel(const float* __restrict__ x,
                                                    const float* __restrict__ Wc,
                                                    const float* __restrict__ bias,
                                                    float* __restrict__ out) {
    __shared__ float2 sdata[SROWS][SCOLS];     // 20*118*8 = 18.9 KB
    __shared__ float  glds[STRIP * Wn];        // 1568*4  =  6.3 KB
    __shared__ float  w[98];

    const int tid  = threadIdx.x;
    const int b    = blockIdx.x >> 3;          // NSTRIP == 8
    const int s    = blockIdx.x & 7;
    const int r0   = s * STRIP;
    const int lane = tid & 31;
    const int grp  = tid >> 5;                 // 16 groups of 32 lanes

    if (tid < 98) w[tid] = Wc[tid];
    for (int i = tid; i < SROWS * SCOLS; i += 512)
        ((float2*)sdata)[i] = make_float2(0.f, 0.f);
    __syncthreads();

    const floatx4* __restrict__ x4 = reinterpret_cast<const floatx4*>(x);

    // ---- phase 1: per-pixel channel stats over strip + halo rows ----------
    for (int p = grp; p < SROWS * Wn; p += 16) {
        const int hr = p / Wn;
        const int c  = p % Wn;
        const int gr = r0 - HALO + hr;
        if (gr >= 0 && gr < Hn) {
            floatx4 v = x4[((size_t)(b * Hn + gr) * Wn + c) * 32 + lane];
            float ssum = v.x + v.y + v.z + v.w;
            float smax = fmaxf(fmaxf(v.x, v.y), fmaxf(v.z, v.w));
#pragma unroll
            for (int off = 16; off >= 1; off >>= 1) {
                ssum += __shfl_xor(ssum, off);
                smax = fmaxf(smax, __shfl_xor(smax, off));
            }
            if (lane == 0)
                sdata[hr][c + HALO] = make_float2(ssum * (1.0f / 128.0f), smax);
        }
        // out-of-image rows remain zero (exact for SAME zero padding)
    }
    __syncthreads();

    // ---- phase 2: 7x7 conv + bias + sigmoid -> gate in LDS ----------------
    const float bb = bias[0];
    for (int p = tid; p < STRIP * Wn; p += 512) {
        const int r = p / Wn;
        const int c = p % Wn;
        float acc = bb;
#pragma unroll
        for (int kh = 0; kh < 7; ++kh)
#pragma unroll
            for (int kw = 0; kw < 7; ++kw) {
                const float2 sv = sdata[r + kh][c + kw];
                acc = fmaf(sv.x, w[(kh * 7 + kw) * 2 + 0], acc);
                acc = fmaf(sv.y, w[(kh * 7 + kw) * 2 + 1], acc);
            }
        glds[p] = 1.0f / (1.0f + expf(-acc));
    }
    __syncthreads();

    // ---- phase 3: out = x * gate, NT store --------------------------------
    floatx4* __restrict__ o4 = reinterpret_cast<floatx4*>(out);
    const size_t base = ((size_t)(b * Hn + r0) * Wn) * 32;  // float4 index
#pragma unroll 4
    for (int i = tid; i < STRIP * Wn * 32; i += 512) {
        const float g = glds[i >> 5];
        floatx4 v = x4[base + i];
        v *= g;
        __builtin_nontemporal_store(v, &o4[base + i]);
    }
}

extern "C" void kernel_launch(void* const* d_in, const int* in_sizes, int n_in,
                              void* d_out, int out_size, void* d_ws, size_t ws_size,
                              hipStream_t stream) {
    const float* x  = (const float*)d_in[0];
    const float* Wc = (const float*)d_in[1];
    const float* bb = (const float*)d_in[2];
    float* out = (float*)d_out;

    fused_kernel<<<Bn * NSTRIP, 512, 0, stream>>>(x, Wc, bb, out);
}

// Round 5
// 102.584 us; speedup vs baseline: 1.4196x; 1.4196x over previous
//
#include <hip/hip_runtime.h>

// Problem constants: x [32,112,112,128] fp32, W [7,7,2,1] HWIO, b [1]
static constexpr int Bn = 32;
static constexpr int Hn = 112;
static constexpr int Wn = 112;
static constexpr int Cn = 128;                 // channels (32 float4 per pixel)
static constexpr int NPIX = Bn * Hn * Wn;      // 401408 pixels
static constexpr int HALO = 3;

typedef float floatx4 __attribute__((ext_vector_type(4)));

// ---------------------------------------------------------------------------
// K1: per-pixel channel mean + max -> global stats (float2). 32 lanes/pixel,
// float4 per lane, butterfly reduce. Full-occupancy streaming read of x.
// ---------------------------------------------------------------------------
__global__ __launch_bounds__(256) void stats_kernel(const float* __restrict__ x,
                                                    float2* __restrict__ stats) {
    const int tid  = blockIdx.x * blockDim.x + threadIdx.x;
    const int pix  = tid >> 5;
    const int lane = tid & 31;
    const floatx4* __restrict__ x4 = reinterpret_cast<const floatx4*>(x);

    floatx4 v = x4[(size_t)pix * 32 + lane];
    float s = v.x + v.y + v.z + v.w;
    float m = fmaxf(fmaxf(v.x, v.y), fmaxf(v.z, v.w));

#pragma unroll
    for (int off = 16; off >= 1; off >>= 1) {
        s += __shfl_xor(s, off);
        m = fmaxf(m, __shfl_xor(m, off));
    }
    if (lane == 0) {
        stats[pix] = make_float2(s * (1.0f / 128.0f), m);
    }
}

// ---------------------------------------------------------------------------
// K2: fused conv + sigmoid + multiply. Block = one image row (b, r).
// Phase A: load stats rows r-3..r+3 (zero outside) into LDS, cols zero-padded.
// Phase B: 112 threads compute the 7x7x2 conv + bias + sigmoid -> gate in LDS.
// Phase C: all 256 threads stream the row's x (3584 float4), multiply by
//          gate, non-temporal store. 4 waves/block, ~8 blocks/CU resident ->
//          conv phases of one block overlap multiply phases of others.
// ---------------------------------------------------------------------------
__global__ __launch_bounds__(256) void conv_mul_kernel(const float* __restrict__ x,
                                                       const float2* __restrict__ stats,
                                                       const float* __restrict__ Wc,
                                                       const float* __restrict__ bias,
                                                       float* __restrict__ out) {
    __shared__ float2 sdat[7][Wn + 2 * HALO];  // 7 x 118 float2, zero-padded cols
    __shared__ float  glds[Wn];                // gate for this row
    __shared__ float  w[98];

    const int tid = threadIdx.x;
    const int r   = blockIdx.x % Hn;           // image row
    const int b   = blockIdx.x / Hn;           // image

    if (tid < 98) w[tid] = Wc[tid];
    // zero the padded stat tile (7*118 = 826 float2)
    for (int i = tid; i < 7 * (Wn + 2 * HALO); i += 256)
        ((float2*)sdat)[i] = make_float2(0.f, 0.f);
    __syncthreads();

    // Phase A: stats rows r-3 .. r+3 for this image
    for (int p = tid; p < 7 * Wn; p += 256) {
        const int kr = p / Wn;                 // 0..6
        const int c  = p % Wn;
        const int rr = r - HALO + kr;
        if (rr >= 0 && rr < Hn)
            sdat[kr][c + HALO] = stats[(size_t)(b * Hn + rr) * Wn + c];
    }
    __syncthreads();

    // Phase B: conv + bias + sigmoid for the row's 112 pixels
    if (tid < Wn) {
        float acc = bias[0];
#pragma unroll
        for (int kh = 0; kh < 7; ++kh)
#pragma unroll
            for (int kw = 0; kw < 7; ++kw) {
                const float2 sv = sdat[kh][tid + kw];
                acc = fmaf(sv.x, w[(kh * 7 + kw) * 2 + 0], acc);
                acc = fmaf(sv.y, w[(kh * 7 + kw) * 2 + 1], acc);
            }
        glds[tid] = 1.0f / (1.0f + expf(-acc));
    }
    __syncthreads();

    // Phase C: out = x * gate for this row (3584 float4)
    const floatx4* __restrict__ x4 = reinterpret_cast<const floatx4*>(x);
    floatx4* __restrict__ o4 = reinterpret_cast<floatx4*>(out);
    const size_t base = ((size_t)(b * Hn + r) * Wn) * 32;   // float4 index
#pragma unroll 2
    for (int i = tid; i < Wn * 32; i += 256) {
        const float g = glds[i >> 5];
        floatx4 v = x4[base + i];
        v *= g;
        __builtin_nontemporal_store(v, &o4[base + i]);
    }
}

extern "C" void kernel_launch(void* const* d_in, const int* in_sizes, int n_in,
                              void* d_out, int out_size, void* d_ws, size_t ws_size,
                              hipStream_t stream) {
    const float* x  = (const float*)d_in[0];
    const float* Wc = (const float*)d_in[1];
    const float* bb = (const float*)d_in[2];
    float* out = (float*)d_out;

    float2* stats = (float2*)d_ws;             // NPIX float2 = 3.2 MB

    // K1: 32 threads/pixel
    stats_kernel<<<(NPIX * 32) / 256, 256, 0, stream>>>(x, stats);
    // K2: one block per image row
    conv_mul_kernel<<<Bn * Hn, 256, 0, stream>>>(x, stats, Wc, bb, out);
}